// Round 14
// baseline (883.285 us; speedup 1.0000x reference)
//
#include <hip/hip_runtime.h>

typedef _Float16 f16;
typedef __attribute__((ext_vector_type(8))) _Float16 f16x8;
typedef __attribute__((ext_vector_type(4))) _Float16 f16x4;
typedef __attribute__((ext_vector_type(2))) _Float16 f16x2;
typedef __attribute__((ext_vector_type(4))) float f32x4;

// ---------------- unified MFMA GEMM v5: 128x128 block tile, 2x2 waves of 64x64 tiles,
// acc[4][4]=64 VGPR, 4 blocks/CU. TWO-PASS capable: acc = A@Bt + A2@Bt2 (A2 null -> single).
// All Kd MULTIPLES OF 64. XCD-chunked 1-D grid decode (T1).
// r14: epilogue stores widened to 16B/lane (f16x8) — full write-sector coverage;
// the single straddling 64-col window (556 boundary, %8==4) is split explicitly.
// mode 0: single dest Cb (vector) or Cf (scalar fp32) + optional bnsum stats
// mode 1: routing cols [0,256)->hbD(ld256) [256,556)->tbufD(ld320,relu;colsum [256,456)) [556,656)->xcatD(ld384,relu)
__global__ __launch_bounds__(256, 4) void gemm5(
    const f16* __restrict__ A, int lda, const f16* __restrict__ Bt, int Kd,
    const f16* __restrict__ A2, int lda2, const f16* __restrict__ Bt2, int Kd2,
    const float* __restrict__ bias,
    f16* __restrict__ Cb, float* __restrict__ Cf, int ldc,
    int R, int ncols, int relu,
    float* __restrict__ csbuf,
    float* __restrict__ bnsum_ptr,
    f16* __restrict__ hbD, f16* __restrict__ tbufD, f16* __restrict__ xcatD,
    int mode, int nrt, int ncb)
{
    const int grpsz   = ncb << 3;
    const int grp     = blockIdx.x / grpsz;
    const int w       = blockIdx.x - grp * grpsz;
    const int rowtile = (grp << 3) + (w & 7);
    const int coltile = w >> 3;
    if (rowtile >= nrt) return;

    __shared__ char smem[36864];        // 36 KB -> 4 blocks/CU
    f16* As = (f16*)smem;               // [128][72]
    f16* Bs = (f16*)(smem + 18432);     // [128][72]
    float* scr = (float*)(smem + 34816);

    const int tid  = threadIdx.x;
    const int wid  = tid >> 6;
    const int lane = tid & 63;
    const int m    = lane & 15;
    const int quad = lane >> 4;
    const int wr   = wid >> 1;
    const int wc   = wid & 1;

    const long rowblk  = (long)rowtile * 128;
    const int  colbase = coltile * 128;

    f32x4 acc[4][4];
#pragma unroll
    for (int rt = 0; rt < 4; ++rt)
#pragma unroll
        for (int ct = 0; ct < 4; ++ct)
            acc[rt][ct] = f32x4{0.f, 0.f, 0.f, 0.f};

    for (int pass = 0; pass < 2; ++pass) {
        const f16* Ap; const f16* Bp; int ldap, Kdp;
        if (pass == 0) { Ap = A;  Bp = Bt;  ldap = lda;  Kdp = Kd;  }
        else           { Ap = A2; Bp = Bt2; ldap = lda2; Kdp = Kd2; }
        if (!Ap) break;
        for (int k0 = 0; k0 < Kdp; k0 += 64) {
            if (pass || k0) __syncthreads();
#pragma unroll
            for (int i = 0; i < 4; ++i) {                  // A: 128 rows x 64
                int u = i * 256 + tid;
                int r = u >> 3, s = u & 7;
                long rr = rowblk + r; if (rr > (long)R - 1) rr = (long)R - 1;
                *(f16x8*)&As[r * 72 + s * 8] = *(const f16x8*)(Ap + rr * (long)ldap + k0 + s * 8);
            }
#pragma unroll
            for (int i = 0; i < 4; ++i) {                  // B: 128 cols x 64
                int u = i * 256 + tid;
                int c = u >> 3, s = u & 7;
                *(f16x8*)&Bs[c * 72 + s * 8] =
                    *(const f16x8*)(Bp + (long)(colbase + c) * Kdp + k0 + s * 8);
            }
            __syncthreads();
#pragma unroll 2
            for (int kk = 0; kk < 64; kk += 32) {
                f16x8 a[4], b[4];
#pragma unroll
                for (int rt = 0; rt < 4; ++rt)
                    a[rt] = *(const f16x8*)&As[(wr * 64 + rt * 16 + m) * 72 + kk + quad * 8];
#pragma unroll
                for (int ct = 0; ct < 4; ++ct)
                    b[ct] = *(const f16x8*)&Bs[(wc * 64 + ct * 16 + m) * 72 + kk + quad * 8];
#pragma unroll
                for (int ct = 0; ct < 4; ++ct)
#pragma unroll
                    for (int rt = 0; rt < 4; ++rt)
                        acc[rt][ct] = __builtin_amdgcn_mfma_f32_16x16x32_f16(a[rt], b[ct], acc[rt][ct], 0, 0, 0);
            }
        }
    }

    __syncthreads();                    // staging reads done; smem reused for epilogue

    if (mode == 0 && Cf) {
        // exact-fp32 output path (final layer): scalar stores
#pragma unroll
        for (int ct = 0; ct < 4; ++ct) {
            int col = colbase + wc * 64 + ct * 16 + m;
            if (col >= ncols) continue;
            float bv = bias ? bias[col] : 0.f;
#pragma unroll
            for (int rt = 0; rt < 4; ++rt) {
#pragma unroll
                for (int r = 0; r < 4; ++r) {
                    long row = rowblk + wr * 64 + rt * 16 + quad * 4 + r;
                    if (row < R) {
                        float v = acc[rt][ct][r] + bv;
                        if (relu && v < 0.f) v = 0.f;
                        Cf[row * (long)ldc + col] = v;
                    }
                }
            }
        }
        return;
    }

    float rsum[4], rsq[4];
#pragma unroll
    for (int ct = 0; ct < 4; ++ct) { rsum[ct] = 0.f; rsq[ct] = 0.f; }

    f16* epw = (f16*)smem + wid * (64 * 68);   // wave-private 64x68 f16 tile

    const bool needsum = (mode == 1) ? (colbase == 256 || colbase == 384)
                                     : (bnsum_ptr != nullptr);

#pragma unroll
    for (int ct = 0; ct < 4; ++ct) {
        int col = colbase + wc * 64 + ct * 16 + m;
        float bv;
        if (mode == 1) bv = bias[col];                     // biascat[656..768)=0 (prep)
        else           bv = (bias && col < ncols) ? bias[col] : 0.f;
        bool isrelu = (mode == 1) ? (col >= 256) : (relu != 0);
#pragma unroll
        for (int rt = 0; rt < 4; ++rt) {
#pragma unroll
            for (int r = 0; r < 4; ++r) {
                long row = rowblk + wr * 64 + rt * 16 + quad * 4 + r;
                float v = acc[rt][ct][r] + bv;
                if (isrelu && v < 0.f) v = 0.f;
                if (needsum && row < R && col < ((mode == 1) ? 656 : ncols)) {
                    rsum[ct] += v;
                    rsq[ct]  += v * v;
                }
                epw[(rt * 16 + quad * 4 + r) * 68 + ct * 16 + m] = (f16)v;
            }
        }
    }

    // 16B/lane coalesced stores: 8 lanes x f16x8 = 128B per row, 8 rows/instruction
#pragma unroll
    for (int it = 0; it < 8; ++it) {
        int rl = it * 8 + (lane >> 3);
        int ch = lane & 7;
        long grow = rowblk + wr * 64 + rl;
        if (grow >= R) continue;
        f16x8 vv = *(const f16x8*)&epw[rl * 68 + ch * 8];
        int c8 = colbase + wc * 64 + ch * 8;
        if (mode == 1) {
            if (c8 < 256) {
                *(f16x8*)&hbD[grow * 256L + c8] = vv;
            } else if (c8 + 7 < 556) {
                *(f16x8*)&tbufD[grow * 320L + (c8 - 256)] = vv;
            } else if (c8 < 556) {                     // c8 == 552: 4 cols tbuf + 4 cols xcat
                f16x4 lo, hi;
#pragma unroll
                for (int j = 0; j < 4; ++j) { lo[j] = vv[j]; hi[j] = vv[4 + j]; }
                *(f16x4*)&tbufD[grow * 320L + (c8 - 256)] = lo;
                *(f16x4*)&xcatD[grow * 384L + (c8 + 4 - 556)] = hi;
            } else if (c8 < 656) {
                *(f16x8*)&xcatD[grow * 384L + (c8 - 556)] = vv;
            }
        } else {
            if (c8 + 8 <= ncols) {
                *(f16x8*)&Cb[grow * (long)ldc + c8] = vv;
            } else if (c8 + 4 <= ncols) {              // partial tail (unused at ncols=256)
                f16x4 lo;
#pragma unroll
                for (int j = 0; j < 4; ++j) lo[j] = vv[j];
                *(f16x4*)&Cb[grow * (long)ldc + c8] = lo;
            }
        }
    }

    if (needsum) {
        __syncthreads();
#pragma unroll
        for (int ct = 0; ct < 4; ++ct) {
            float s = rsum[ct];
            s += __shfl_xor(s, 16);
            s += __shfl_xor(s, 32);
            float q = rsq[ct];
            q += __shfl_xor(q, 16);
            q += __shfl_xor(q, 32);
            if (quad == 0) {
                scr[wr * 128 + wc * 64 + ct * 16 + m]       = s;
                scr[256 + wr * 128 + wc * 64 + ct * 16 + m] = q;
            }
        }
        __syncthreads();
        if (tid < 128) {
            int gcol = colbase + tid;
            float s = scr[tid] + scr[128 + tid];
            if (mode == 1) {
                if (gcol >= 256 && gcol < 456) atomicAdd(&csbuf[gcol - 256], s);
            } else if (gcol < ncols) {
                float q = scr[256 + tid] + scr[384 + tid];
                atomicAdd(&bnsum_ptr[gcol], s);
                atomicAdd(&bnsum_ptr[256 + gcol], q);
            }
        }
    }
}

// ---------------- W_U = Mscaled @ rw1 (100 x dou), B-operand layout [dou][128] f16.
__global__ __launch_bounds__(256) void wu_kernel(const f16* __restrict__ MT,
                                                 const float* __restrict__ rwf, int dou,
                                                 f16* __restrict__ WUT)
{
    int idx = blockIdx.x * 256 + threadIdx.x;
    if (idx >= (dou << 7)) return;
    int a = idx & 127, d = idx >> 7;
    float s = 0.f;
    if (a < 100) {
#pragma unroll 4
        for (int c = 0; c < 100; ++c)
            s += (float)MT[c * 128 + a] * rwf[(long)c * dou + d];
    }
    WUT[d * 128 + a] = (f16)s;
}

// ---------------- one-shot prep: weight transposes, x0 cast, zero-fills, biascat init
struct PrepJobs {
    const float* src[16];
    void*        dst[16];
    int   K[16], ncols[16], Kd[16], type[16];
    long  start[16], elems[16];
    int   njobs;
};

__global__ __launch_bounds__(256) void prep_all(PrepJobs J)
{
    long b = blockIdx.x;
    int j = 0;
    for (int i = 1; i < J.njobs; ++i)
        if (b >= J.start[i]) j = i;
    long idx = (b - J.start[j]) * 256 + threadIdx.x;
    if (idx >= J.elems[j]) return;
    int ty = J.type[j];
    if (ty == 0) {                       // transpose fp32[K][ncols] -> f16[idx/Kd][idx%Kd]
        int Kd = J.Kd[j];
        int k = (int)(idx % Kd);
        long n = idx / Kd;
        float v = (k < J.K[j] && n < J.ncols[j]) ? J.src[j][(long)k * J.ncols[j] + n] : 0.f;
        ((f16*)J.dst[j])[idx] = (f16)v;
    } else if (ty == 1) {                // cast fp32 -> f16
        ((f16*)J.dst[j])[idx] = (f16)J.src[j][idx];
    } else if (ty == 2) {                // zero floats
        ((float*)J.dst[j])[idx] = 0.f;
    } else if (ty == 3) {                // biascat init: [0(256) | abv0(400) | 0(112)]
        float v = (idx >= 256 && idx < 656) ? J.src[j][idx - 256] : 0.f;
        ((float*)J.dst[j])[idx] = v;
    } else {                             // ty 4: zero f16 strided cols: ld=K, start=ncols, w=Kd
        int w = J.Kd[j];
        long row = idx / w;
        int col = J.ncols[j] + (int)(idx % w);
        ((f16*)J.dst[j])[row * J.K[j] + col] = (f16)0.f;
    }
}

// ---------------- CSR build: hist + 3-phase parallel scan + scatter
__global__ void hist_kernel(const int* __restrict__ dst, int E, int* __restrict__ cnt)
{
    int e = blockIdx.x * 256 + threadIdx.x;
    if (e < E) atomicAdd(&cnt[dst[e]], 1);
}

__global__ __launch_bounds__(1024) void scanA_kernel(const int* __restrict__ cnt, int n,
                                                     int* __restrict__ csum)
{
    __shared__ int sdata[1024];
    int t = threadIdx.x;
    int i = blockIdx.x * 1024 + t;
    sdata[t] = (i < n) ? cnt[i] : 0;
    __syncthreads();
    for (int d = 512; d > 0; d >>= 1) {
        if (t < d) sdata[t] += sdata[t + d];
        __syncthreads();
    }
    if (t == 0) csum[blockIdx.x] = sdata[0];
}

__global__ void scanB_kernel(int* __restrict__ csum, int nchunks, int n, int* __restrict__ rowptr)
{
    if (threadIdx.x == 0) {
        int run = 0;
        for (int b = 0; b < nchunks; ++b) {
            int v = csum[b];
            csum[b] = run;
            run += v;
        }
        rowptr[n] = run;
    }
}

__global__ __launch_bounds__(1024) void scanC_kernel(const int* __restrict__ cnt, int n,
                                                     const int* __restrict__ csum,
                                                     int* __restrict__ rowptr,
                                                     int* __restrict__ cursor,
                                                     float* __restrict__ dis)
{
    __shared__ int sdata[1024];
    int t = threadIdx.x;
    int i = blockIdx.x * 1024 + t;
    int v = (i < n) ? cnt[i] : 0;
    sdata[t] = v;
    __syncthreads();
    for (int d = 1; d < 1024; d <<= 1) {
        int x = (t >= d) ? sdata[t - d] : 0;
        __syncthreads();
        sdata[t] += x;
        __syncthreads();
    }
    if (i < n) {
        int excl = csum[blockIdx.x] + sdata[t] - v;
        rowptr[i] = excl;
        cursor[i] = excl;
        dis[i] = rsqrtf((float)(v + 1));   // deg = in-degree + self-loop
    }
}

__global__ void scatter_kernel(const int* __restrict__ src, const int* __restrict__ dst,
                               int E, int* __restrict__ cursor, int* __restrict__ colidx)
{
    int e = blockIdx.x * 256 + threadIdx.x;
    if (e < E) {
        int d = dst[e];
        int pos = atomicAdd(&cursor[d], 1);
        colidx[pos] = src[e];
    }
}

// ---------------- GCN aggregation: one wave per dst node, f16 h, 4x edge unroll
// (r11-proven form: 61.5 us; r12's half-wave pairing regressed -> reverted)
__global__ __launch_bounds__(256) void agg_kernel(
    const f16* __restrict__ h, const int* __restrict__ rowptr,
    const int* __restrict__ colidx, const float* __restrict__ dis,
    const float* __restrict__ cb, f16* __restrict__ out, int ldc, int R)
{
    int wid = threadIdx.x >> 6, lane = threadIdx.x & 63;
    int i = blockIdx.x * 4 + wid;
    if (i >= R) return;
    float disi = dis[i];
    f16x4 hv = *(const f16x4*)(h + (long)i * 256 + lane * 4);
    float acc[4];
#pragma unroll
    for (int j = 0; j < 4; ++j) acc[j] = (float)hv[j] * disi;  // self loop
    int e0 = rowptr[i], e1 = rowptr[i + 1];
    int e = e0;
    for (; e + 3 < e1; e += 4) {
        int s0 = colidx[e], s1 = colidx[e + 1], s2 = colidx[e + 2], s3 = colidx[e + 3];
        float w0 = dis[s0], w1 = dis[s1], w2 = dis[s2], w3 = dis[s3];
        f16x4 h0 = *(const f16x4*)(h + (long)s0 * 256 + lane * 4);
        f16x4 h1 = *(const f16x4*)(h + (long)s1 * 256 + lane * 4);
        f16x4 h2 = *(const f16x4*)(h + (long)s2 * 256 + lane * 4);
        f16x4 h3 = *(const f16x4*)(h + (long)s3 * 256 + lane * 4);
#pragma unroll
        for (int j = 0; j < 4; ++j)
            acc[j] += (float)h0[j] * w0 + (float)h1[j] * w1
                    + (float)h2[j] * w2 + (float)h3[j] * w3;
    }
    for (; e < e1; ++e) {
        int s = colidx[e];
        float w = dis[s];
        f16x4 hs = *(const f16x4*)(h + (long)s * 256 + lane * 4);
#pragma unroll
        for (int j = 0; j < 4; ++j) acc[j] += (float)hs[j] * w;
    }
    f16x4 o;
#pragma unroll
    for (int j = 0; j < 4; ++j) {
        float v = acc[j] * disi + cb[lane * 4 + j];
        if (v < 0.f) v = 0.f;
        o[j] = (f16)v;
    }
    *(f16x4*)(out + (long)i * ldc + lane * 4) = o;
}

// ---------------- M = V^T Z via MFMA, two-stage, no atomics
#define VTZ_BLOCKS 192
__global__ __launch_bounds__(256) void vtz_mfma(const f16* __restrict__ t, int ld, int R,
                                                float* __restrict__ Mpart)
{
    __shared__ f16 Vt[112 * 72];
    __shared__ f16 Zt[112 * 72];
    const int tid  = threadIdx.x;
    const int wid  = tid >> 6;
    const int lane = tid & 63;
    const int m    = lane & 15;
    const int quad = lane >> 4;

    for (int idx = tid; idx < 12 * 64; idx += 256) {
        int c = 100 + (idx >> 6), r = idx & 63;
        Vt[c * 72 + r] = (f16)0.f;
        Zt[c * 72 + r] = (f16)0.f;
    }

    f32x4 acc[2][7];
#pragma unroll
    for (int rt = 0; rt < 2; ++rt)
#pragma unroll
        for (int ct = 0; ct < 7; ++ct)
            acc[rt][ct] = f32x4{0.f, 0.f, 0.f, 0.f};

    for (long base = (long)blockIdx.x * 64; base < R; base += (long)gridDim.x * 64) {
        __syncthreads();
        for (int idx = tid; idx < 50 * 64; idx += 256) {
            int r = idx / 50, c2 = (idx - r * 50) * 2;
            f16x2 v2 = f16x2{(f16)0.f, (f16)0.f};
            f16x2 z2 = f16x2{(f16)0.f, (f16)0.f};
            if (base + r < R) {
                v2 = *(const f16x2*)(t + (base + r) * ld + 100 + c2);
                z2 = *(const f16x2*)(t + (base + r) * ld + 200 + c2);
            }
            Vt[c2 * 72 + r] = v2[0]; Vt[(c2 + 1) * 72 + r] = v2[1];
            Zt[c2 * 72 + r] = z2[0]; Zt[(c2 + 1) * 72 + r] = z2[1];
        }
        __syncthreads();
#pragma unroll
        for (int ks = 0; ks < 2; ++ks) {
            int k0 = ks * 32 + quad * 8;
            f16x8 b[7];
#pragma unroll
            for (int ct = 0; ct < 7; ++ct)
                b[ct] = *(const f16x8*)&Zt[(ct * 16 + m) * 72 + k0];
#pragma unroll
            for (int rt = 0; rt < 2; ++rt) {
                int tr = wid + rt * 4;
                if (tr >= 7) continue;
                f16x8 a = *(const f16x8*)&Vt[(tr * 16 + m) * 72 + k0];
#pragma unroll
                for (int ct = 0; ct < 7; ++ct)
                    acc[rt][ct] = __builtin_amdgcn_mfma_f32_16x16x32_f16(a, b[ct], acc[rt][ct], 0, 0, 0);
            }
        }
    }

    float* out = Mpart + (long)blockIdx.x * 10000;
#pragma unroll
    for (int rt = 0; rt < 2; ++rt) {
        int tr = wid + rt * 4;
        if (tr >= 7) continue;
#pragma unroll
        for (int ct = 0; ct < 7; ++ct) {
            int b = ct * 16 + m;
            if (b >= 100) continue;
#pragma unroll
            for (int r = 0; r < 4; ++r) {
                int a = tr * 16 + quad * 4 + r;
                if (a < 100) out[a * 100 + b] = acc[rt][ct][r];
            }
        }
    }
}

// reduce Mpart; compute 1/nf scale inline from csbuf; emit MT = (M*scale)^T as f16.
__global__ __launch_bounds__(256) void vtz_reduce2(const float* __restrict__ Mpart,
                                                   f16* __restrict__ MT,
                                                   const float* __restrict__ cs, int R)
{
    __shared__ float s2[256];
    int t = threadIdx.x;
    float v = (t < 100) ? cs[t] * cs[100 + t] : 0.f;
    s2[t] = v;
    __syncthreads();
    for (int d = 128; d > 0; d >>= 1) {
        if (t < d) s2[t] += s2[t + d];
        __syncthreads();
    }
    float scale = 1.0f / (s2[0] / (float)R + 1e-6f);

    int idx = blockIdx.x * 256 + t;
    if (idx >= 10000) return;
    float s = 0.f;
    for (int b = 0; b < VTZ_BLOCKS; ++b) s += Mpart[(long)b * 10000 + idx];
    s *= scale;
    int a = idx / 100, c = idx - a * 100;     // M[a][c]
    MT[c * 128 + a] = (f16)s;                 // MT[n*128+k] = M[k][n] * scale
}

// ---------------- merged BN finalize + fold
__global__ __launch_bounds__(256) void bn_fold2(
    f16* __restrict__ bigBT,
    const float* __restrict__ cwf, const float* __restrict__ awf,
    const float* __restrict__ bnsum, const float* __restrict__ g,
    const float* __restrict__ bt, int R,
    const float* __restrict__ ab0, float* __restrict__ biascat)
{
    __shared__ float a_s[256], b_s[256];
    const int t = threadIdx.x;
    {
        float s0 = bnsum[t];
        float s1 = bnsum[256 + t];
        float mean = s0 / (float)R;
        float var  = s1 / (float)R - mean * mean;
        if (var < 0.f) var = 0.f;
        float a = g[t] * rsqrtf(var + 1e-5f);
        a_s[t] = a;
        b_s[t] = bt[t] - mean * a;
    }
    __syncthreads();
    const int bid = blockIdx.x;
    if (bid < 768) {
        long idx = (long)bid * 256 + t;              // idx & 255 == t
        bigBT[idx] = (f16)((float)bigBT[idx] * a_s[t]);
    } else if (bid == 768) {
        float s = 0.f;
        for (int k = 0; k < 256; ++k) s += b_s[k] * cwf[(long)k * 256 + t];
        biascat[t] = s;
    } else {
        int n = (bid - 769) * 256 + t;
        if (n < 400) {
            float s = ab0[n];
            for (int k = 0; k < 256; ++k) s += b_s[k] * awf[(long)k * 400 + n];
            biascat[256 + n] = s;
        }
    }
}

// =====================================================================================
extern "C" void kernel_launch(void* const* d_in, const int* in_sizes, int n_in,
                              void* d_out, int out_size, void* d_ws, size_t ws_size,
                              hipStream_t stream)
{
    (void)n_in; (void)out_size; (void)ws_size;
    const int N = in_sizes[0] / 128;       // 50000
    const int E = in_sizes[1] / 2;         // 800000

    const float* x0 = (const float*)d_in[0];
    const int*  ei   = (const int*)d_in[1];
    const int*  esrc = ei;
    const int*  edst = ei + E;
    const float *cw[3], *cbv[3], *aw[3], *abv[3], *rw[3], *rbv[3];
    for (int l = 0; l < 3; ++l) {
        cw[l]  = (const float*)d_in[2 + 6 * l];
        cbv[l] = (const float*)d_in[3 + 6 * l];
        aw[l]  = (const float*)d_in[4 + 6 * l];
        abv[l] = (const float*)d_in[5 + 6 * l];
        rw[l]  = (const float*)d_in[6 + 6 * l];
        rbv[l] = (const float*)d_in[7 + 6 * l];
    }
    const float* g[2]   = {(const float*)d_in[20], (const float*)d_in[22]};
    const float* btb[2] = {(const float*)d_in[21], (const float*)d_in[23]};

    // ---- workspace carve ----
    char* p = (char*)d_ws;
    auto carve = [&](size_t bytes) -> char* {
        char* r = p; p += (bytes + 255) & ~(size_t)255; return r;
    };
    int*   cnt    = (int*)carve((size_t)N * 4);
    int*   rowptr = (int*)carve((size_t)(N + 1) * 4);
    int*   cursor = (int*)carve((size_t)N * 4);
    int*   colidx = (int*)carve((size_t)E * 4);
    float* dis    = (float*)carve((size_t)N * 4);
    int*   csum   = (int*)carve(256 * 4);
    float* Mpart  = (float*)carve((size_t)VTZ_BLOCKS * 10000 * 4);
    // zero region: csbuf0/1/2, bnsumA/B, MT pad
    float* zr     = (float*)carve(9984 * 4);
    float* csbufL[3] = {zr, zr + 256, zr + 512};
    float* bnsumA = zr + 768;
    float* bnsumB = zr + 1280;
    f16*   MT     = (f16*)(zr + 1792);            // 16384 f16
    float* biascat = (float*)carve(768 * 4);
    f16*   WUT    = (f16*)carve(256 * 128 * 2);   // W_U^T [dou][128]
    f16*   bigBT[3], *rwT2[3];
    int din[3] = {128, 256, 256};
    int dou[3] = {256, 256, 128};
    for (int l = 0; l < 3; ++l) {
        bigBT[l] = (f16*)carve((size_t)768 * din[l] * 2);
        rwT2[l]  = (f16*)carve((size_t)dou[l] * 384 * 2);   // rw rows 100..455 -> [dou][384]
    }
    f16*   xbf  = (f16*)carve((size_t)N * 256 * 2);         // current x; pre-BN y for l>=1
    f16*   hb   = (f16*)carve((size_t)N * 256 * 2);
    f16*   tbuf = (f16*)carve((size_t)N * 320 * 2);         // U|V|Z (ld=320, 640B rows)
    f16*   xcat2 = (f16*)carve(((size_t)N * 384 + 64) * 2); // [T|xloc|pad], ld=384 (768B rows)

    // ---- build prep job list ----
    PrepJobs J{};
    int nj = 0; long blk = 0;
    auto addJob = [&](const float* s, void* d, int K, int nc, int Kd, int ty, long elems) {
        J.src[nj] = s; J.dst[nj] = d; J.K[nj] = K; J.ncols[nj] = nc; J.Kd[nj] = Kd;
        J.type[nj] = ty; J.start[nj] = blk; J.elems[nj] = elems;
        blk += (elems + 255) / 256; ++nj;
    };
    for (int l = 0; l < 3; ++l)   // cw -> bigBT cols [0,256)
        addJob(cw[l], bigBT[l], din[l], 256, din[l], 0, (long)256 * din[l]);
    for (int l = 0; l < 3; ++l)   // aw -> bigBT cols [256,768), 400 real + zero pad
        addJob(aw[l], bigBT[l] + (long)256 * din[l], din[l], 400, din[l], 0, (long)512 * din[l]);
    for (int l = 0; l < 3; ++l)   // rw rows 100..455 -> rwT2 [dou][384] (rows 356..383 zero)
        addJob(rw[l] + (long)100 * dou[l], rwT2[l], 356, dou[l], 384, 0, (long)dou[l] * 384);
    addJob(x0, xbf, 0, 0, 0, 1, (long)N * 128);   // cast
    addJob(nullptr, zr, 0, 0, 0, 2, 9984);        // zero csbufs/bnsums/MT
    addJob(nullptr, cnt, 0, 0, 0, 2, N);          // zero cnt (for hist)
    addJob(abv[0], biascat, 0, 0, 0, 3, 768);     // biascat init (layer 0)
    addJob(nullptr, xcat2, 384, 356, 28, 4, (long)N * 28);  // zero xcat2 junk cols 356..383
    J.njobs = nj;

    prep_all<<<(unsigned)blk, 256, 0, stream>>>(J);

    // ---- CSR build ----
    const int nchunks = (N + 1023) / 1024;
    hist_kernel<<<(E + 255) / 256, 256, 0, stream>>>(edst, E, cnt);
    scanA_kernel<<<nchunks, 1024, 0, stream>>>(cnt, N, csum);
    scanB_kernel<<<1, 64, 0, stream>>>(csum, nchunks, N, rowptr);
    scanC_kernel<<<nchunks, 1024, 0, stream>>>(cnt, N, csum, rowptr, cursor, dis);
    scatter_kernel<<<(E + 255) / 256, 256, 0, stream>>>(esrc, edst, E, cursor, colidx);

    int lda = 128;
    const int nrt = (N + 127) / 128;                     // 391 row tiles
    auto grid = [&](int ncb) -> unsigned {
        return (unsigned)(((nrt + 7) / 8) * 8 * ncb);    // padded to XCD groups
    };

    for (int l = 0; l < 3; ++l) {
        float* bnsumX = (l == 0) ? bnsumA : bnsumB;

        // 1) fused: [h | U|V|Z | T] = x @ [cw|aw] (+biascat), colsum fused
        gemm5<<<grid(6), 256, 0, stream>>>(xbf, lda, bigBT[l], din[l],
                                           nullptr, 0, nullptr, 0,
                                           biascat,
                                           nullptr, nullptr, 0, N, 656, 0,
                                           csbufL[l], nullptr,
                                           hb, tbuf, xcat2, 1, nrt, 6);
        // 2) M = V^T Z; reduce computes 1/nf inline -> MT; W_U = Mscaled @ rw1
        vtz_mfma<<<VTZ_BLOCKS, 256, 0, stream>>>(tbuf, 320, N, Mpart);
        vtz_reduce2<<<40, 256, 0, stream>>>(Mpart, MT, csbufL[l], N);
        wu_kernel<<<(dou[l] * 128 + 255) / 256, 256, 0, stream>>>(MT, rw[l], dou[l], WUT);
        // 3) x_local = relu(agg + cb) -> xcat2 cols 100..355
        agg_kernel<<<(N + 3) / 4, 256, 0, stream>>>(hb, rowptr, colidx, dis, cbv[l],
                                                    xcat2 + 100, 384, N);
        // 4) readout: out = U@W_U + [T|xloc]@rw23 (+rb); res never materialized
        if (l < 2) {
            gemm5<<<grid(2), 256, 0, stream>>>(tbuf, 320, WUT, 128,
                                               xcat2, 384, rwT2[l], 384,
                                               rbv[l],
                                               xbf, nullptr, 256, N, 256, 1,
                                               nullptr, bnsumX,
                                               nullptr, nullptr, nullptr, 0, nrt, 2);
            bn_fold2<<<771, 256, 0, stream>>>(bigBT[l + 1], cw[l + 1], aw[l + 1],
                                              bnsumX, g[l], btb[l], N,
                                              abv[l + 1], biascat);
            lda = 256;
        } else {
            gemm5<<<grid(1), 256, 0, stream>>>(tbuf, 320, WUT, 128,
                                               xcat2, 384, rwT2[l], 384,
                                               rbv[l],
                                               nullptr, (float*)d_out, 128, N, 128, 0,
                                               nullptr, nullptr,
                                               nullptr, nullptr, nullptr, 0, nrt, 1);
        }
    }
}

// Round 15
// 846.767 us; speedup vs baseline: 1.0431x; 1.0431x over previous
//
#include <hip/hip_runtime.h>

typedef _Float16 f16;
typedef __attribute__((ext_vector_type(8))) _Float16 f16x8;
typedef __attribute__((ext_vector_type(4))) _Float16 f16x4;
typedef __attribute__((ext_vector_type(2))) _Float16 f16x2;
typedef __attribute__((ext_vector_type(4))) float f32x4;

// ---------------- unified MFMA GEMM v5: 128x128 block tile, 2x2 waves of 64x64 tiles,
// acc[4][4]=64 VGPR, 4 blocks/CU. TWO-PASS capable: acc = A@Bt + A2@Bt2 (A2 null -> single).
// All Kd MULTIPLES OF 64. XCD-chunked 1-D grid decode (T1).
// r15: epilogue reverted to r11-proven 8B f16x4 stores (16B variant regressed);
// fp32 final-output path vectorized via wave-private fp32 LDS transpose (exact values).
// mode 0: single dest Cb (vector) or Cf (vector fp32) + optional bnsum stats
// mode 1: routing cols [0,256)->hbD(ld256) [256,556)->tbufD(ld320,relu;colsum [256,456)) [556,656)->xcatD(ld384,relu)
__global__ __launch_bounds__(256, 4) void gemm5(
    const f16* __restrict__ A, int lda, const f16* __restrict__ Bt, int Kd,
    const f16* __restrict__ A2, int lda2, const f16* __restrict__ Bt2, int Kd2,
    const float* __restrict__ bias,
    f16* __restrict__ Cb, float* __restrict__ Cf, int ldc,
    int R, int ncols, int relu,
    float* __restrict__ csbuf,
    float* __restrict__ bnsum_ptr,
    f16* __restrict__ hbD, f16* __restrict__ tbufD, f16* __restrict__ xcatD,
    int mode, int nrt, int ncb)
{
    const int grpsz   = ncb << 3;
    const int grp     = blockIdx.x / grpsz;
    const int w       = blockIdx.x - grp * grpsz;
    const int rowtile = (grp << 3) + (w & 7);
    const int coltile = w >> 3;
    if (rowtile >= nrt) return;

    __shared__ char smem[36864];        // 36 KB -> 4 blocks/CU
    f16* As = (f16*)smem;               // [128][72]
    f16* Bs = (f16*)(smem + 18432);     // [128][72]
    float* scr = (float*)(smem + 34816);

    const int tid  = threadIdx.x;
    const int wid  = tid >> 6;
    const int lane = tid & 63;
    const int m    = lane & 15;
    const int quad = lane >> 4;
    const int wr   = wid >> 1;
    const int wc   = wid & 1;

    const long rowblk  = (long)rowtile * 128;
    const int  colbase = coltile * 128;

    f32x4 acc[4][4];
#pragma unroll
    for (int rt = 0; rt < 4; ++rt)
#pragma unroll
        for (int ct = 0; ct < 4; ++ct)
            acc[rt][ct] = f32x4{0.f, 0.f, 0.f, 0.f};

    for (int pass = 0; pass < 2; ++pass) {
        const f16* Ap; const f16* Bp; int ldap, Kdp;
        if (pass == 0) { Ap = A;  Bp = Bt;  ldap = lda;  Kdp = Kd;  }
        else           { Ap = A2; Bp = Bt2; ldap = lda2; Kdp = Kd2; }
        if (!Ap) break;
        for (int k0 = 0; k0 < Kdp; k0 += 64) {
            if (pass || k0) __syncthreads();
#pragma unroll
            for (int i = 0; i < 4; ++i) {                  // A: 128 rows x 64
                int u = i * 256 + tid;
                int r = u >> 3, s = u & 7;
                long rr = rowblk + r; if (rr > (long)R - 1) rr = (long)R - 1;
                *(f16x8*)&As[r * 72 + s * 8] = *(const f16x8*)(Ap + rr * (long)ldap + k0 + s * 8);
            }
#pragma unroll
            for (int i = 0; i < 4; ++i) {                  // B: 128 cols x 64
                int u = i * 256 + tid;
                int c = u >> 3, s = u & 7;
                *(f16x8*)&Bs[c * 72 + s * 8] =
                    *(const f16x8*)(Bp + (long)(colbase + c) * Kdp + k0 + s * 8);
            }
            __syncthreads();
#pragma unroll 2
            for (int kk = 0; kk < 64; kk += 32) {
                f16x8 a[4], b[4];
#pragma unroll
                for (int rt = 0; rt < 4; ++rt)
                    a[rt] = *(const f16x8*)&As[(wr * 64 + rt * 16 + m) * 72 + kk + quad * 8];
#pragma unroll
                for (int ct = 0; ct < 4; ++ct)
                    b[ct] = *(const f16x8*)&Bs[(wc * 64 + ct * 16 + m) * 72 + kk + quad * 8];
#pragma unroll
                for (int ct = 0; ct < 4; ++ct)
#pragma unroll
                    for (int rt = 0; rt < 4; ++rt)
                        acc[rt][ct] = __builtin_amdgcn_mfma_f32_16x16x32_f16(a[rt], b[ct], acc[rt][ct], 0, 0, 0);
            }
        }
    }

    __syncthreads();                    // staging reads done; smem reused for epilogue

    if (mode == 0 && Cf) {
        // exact-fp32 output path (final layer): vectorized via wave-private fp32 LDS
        // transpose, two 32-row half-passes (8.5 KB/wave x 4 = 34 KB <= 36 KB).
        float* fpw = (float*)(smem + wid * 8704);
        for (int h = 0; h < 2; ++h) {
#pragma unroll
            for (int ct = 0; ct < 4; ++ct) {
                int col = colbase + wc * 64 + ct * 16 + m;
                float bv = (bias && col < ncols) ? bias[col] : 0.f;
#pragma unroll
                for (int rt2 = 0; rt2 < 2; ++rt2) {
                    int rt = h * 2 + rt2;
#pragma unroll
                    for (int r = 0; r < 4; ++r) {
                        float v = acc[rt][ct][r] + bv;
                        if (relu && v < 0.f) v = 0.f;
                        fpw[(rt2 * 16 + quad * 4 + r) * 68 + ct * 16 + m] = v;
                    }
                }
            }
            // wave-private: compiler-ordered lgkmcnt suffices, no barrier
#pragma unroll
            for (int it = 0; it < 8; ++it) {
                int rl = it * 4 + (lane >> 4);
                int ch = lane & 15;
                long grow = rowblk + wr * 64 + h * 32 + rl;
                int cg = colbase + wc * 64 + ch * 4;
                if (grow < R && cg + 4 <= ncols)
                    *(f32x4*)&Cf[grow * (long)ldc + cg] = *(const f32x4*)&fpw[rl * 68 + ch * 4];
            }
        }
        return;
    }

    float rsum[4], rsq[4];
#pragma unroll
    for (int ct = 0; ct < 4; ++ct) { rsum[ct] = 0.f; rsq[ct] = 0.f; }

    f16* epw = (f16*)smem + wid * (64 * 68);   // wave-private 64x68 f16 tile

    const bool needsum = (mode == 1) ? (colbase == 256 || colbase == 384)
                                     : (bnsum_ptr != nullptr);

#pragma unroll
    for (int ct = 0; ct < 4; ++ct) {
        int col = colbase + wc * 64 + ct * 16 + m;
        float bv;
        if (mode == 1) bv = bias[col];                     // biascat[656..768)=0 (prep)
        else           bv = (bias && col < ncols) ? bias[col] : 0.f;
        bool isrelu = (mode == 1) ? (col >= 256) : (relu != 0);
#pragma unroll
        for (int rt = 0; rt < 4; ++rt) {
#pragma unroll
            for (int r = 0; r < 4; ++r) {
                long row = rowblk + wr * 64 + rt * 16 + quad * 4 + r;
                float v = acc[rt][ct][r] + bv;
                if (isrelu && v < 0.f) v = 0.f;
                if (needsum && row < R && col < ((mode == 1) ? 656 : ncols)) {
                    rsum[ct] += v;
                    rsq[ct]  += v * v;
                }
                epw[(rt * 16 + quad * 4 + r) * 68 + ct * 16 + m] = (f16)v;
            }
        }
    }

    // coalesced stores (r11-proven): 16 lanes x f16x4 = 128B per row; boundaries %4==0
#pragma unroll
    for (int it = 0; it < 16; ++it) {
        int rl = it * 4 + (lane >> 4);
        int ch = lane & 15;
        long grow = rowblk + wr * 64 + rl;
        if (grow >= R) continue;
        f16x4 vv = *(const f16x4*)&epw[rl * 68 + ch * 4];
        int c4 = colbase + wc * 64 + ch * 4;
        if (mode == 1) {
            f16* dst; int ld2, c2;
            if (c4 < 256)      { dst = hbD;   ld2 = 256; c2 = c4; }
            else if (c4 < 556) { dst = tbufD; ld2 = 320; c2 = c4 - 256; }
            else if (c4 < 656) { dst = xcatD; ld2 = 384; c2 = c4 - 556; }
            else continue;
            *(f16x4*)&dst[grow * (long)ld2 + c2] = vv;
        } else {
            if (c4 < ncols)
                *(f16x4*)&Cb[grow * (long)ldc + c4] = vv;
        }
    }

    if (needsum) {
        __syncthreads();
#pragma unroll
        for (int ct = 0; ct < 4; ++ct) {
            float s = rsum[ct];
            s += __shfl_xor(s, 16);
            s += __shfl_xor(s, 32);
            float q = rsq[ct];
            q += __shfl_xor(q, 16);
            q += __shfl_xor(q, 32);
            if (quad == 0) {
                scr[wr * 128 + wc * 64 + ct * 16 + m]       = s;
                scr[256 + wr * 128 + wc * 64 + ct * 16 + m] = q;
            }
        }
        __syncthreads();
        if (tid < 128) {
            int gcol = colbase + tid;
            float s = scr[tid] + scr[128 + tid];
            if (mode == 1) {
                if (gcol >= 256 && gcol < 456) atomicAdd(&csbuf[gcol - 256], s);
            } else if (gcol < ncols) {
                float q = scr[256 + tid] + scr[384 + tid];
                atomicAdd(&bnsum_ptr[gcol], s);
                atomicAdd(&bnsum_ptr[256 + gcol], q);
            }
        }
    }
}

// ---------------- W_U = Mscaled @ rw1 (100 x dou), B-operand layout [dou][128] f16.
__global__ __launch_bounds__(256) void wu_kernel(const f16* __restrict__ MT,
                                                 const float* __restrict__ rwf, int dou,
                                                 f16* __restrict__ WUT)
{
    int idx = blockIdx.x * 256 + threadIdx.x;
    if (idx >= (dou << 7)) return;
    int a = idx & 127, d = idx >> 7;
    float s = 0.f;
    if (a < 100) {
#pragma unroll 4
        for (int c = 0; c < 100; ++c)
            s += (float)MT[c * 128 + a] * rwf[(long)c * dou + d];
    }
    WUT[d * 128 + a] = (f16)s;
}

// ---------------- one-shot prep: weight transposes, x0 cast, zero-fills, biascat init
struct PrepJobs {
    const float* src[16];
    void*        dst[16];
    int   K[16], ncols[16], Kd[16], type[16];
    long  start[16], elems[16];
    int   njobs;
};

__global__ __launch_bounds__(256) void prep_all(PrepJobs J)
{
    long b = blockIdx.x;
    int j = 0;
    for (int i = 1; i < J.njobs; ++i)
        if (b >= J.start[i]) j = i;
    long idx = (b - J.start[j]) * 256 + threadIdx.x;
    if (idx >= J.elems[j]) return;
    int ty = J.type[j];
    if (ty == 0) {                       // transpose fp32[K][ncols] -> f16[idx/Kd][idx%Kd]
        int Kd = J.Kd[j];
        int k = (int)(idx % Kd);
        long n = idx / Kd;
        float v = (k < J.K[j] && n < J.ncols[j]) ? J.src[j][(long)k * J.ncols[j] + n] : 0.f;
        ((f16*)J.dst[j])[idx] = (f16)v;
    } else if (ty == 1) {                // cast fp32 -> f16
        ((f16*)J.dst[j])[idx] = (f16)J.src[j][idx];
    } else if (ty == 2) {                // zero floats
        ((float*)J.dst[j])[idx] = 0.f;
    } else if (ty == 3) {                // biascat init: [0(256) | abv0(400) | 0(112)]
        float v = (idx >= 256 && idx < 656) ? J.src[j][idx - 256] : 0.f;
        ((float*)J.dst[j])[idx] = v;
    } else {                             // ty 4: zero f16 strided cols: ld=K, start=ncols, w=Kd
        int w = J.Kd[j];
        long row = idx / w;
        int col = J.ncols[j] + (int)(idx % w);
        ((f16*)J.dst[j])[row * J.K[j] + col] = (f16)0.f;
    }
}

// ---------------- CSR build: hist + 3-phase parallel scan + scatter
__global__ void hist_kernel(const int* __restrict__ dst, int E, int* __restrict__ cnt)
{
    int e = blockIdx.x * 256 + threadIdx.x;
    if (e < E) atomicAdd(&cnt[dst[e]], 1);
}

__global__ __launch_bounds__(1024) void scanA_kernel(const int* __restrict__ cnt, int n,
                                                     int* __restrict__ csum)
{
    __shared__ int sdata[1024];
    int t = threadIdx.x;
    int i = blockIdx.x * 1024 + t;
    sdata[t] = (i < n) ? cnt[i] : 0;
    __syncthreads();
    for (int d = 512; d > 0; d >>= 1) {
        if (t < d) sdata[t] += sdata[t + d];
        __syncthreads();
    }
    if (t == 0) csum[blockIdx.x] = sdata[0];
}

__global__ void scanB_kernel(int* __restrict__ csum, int nchunks, int n, int* __restrict__ rowptr)
{
    if (threadIdx.x == 0) {
        int run = 0;
        for (int b = 0; b < nchunks; ++b) {
            int v = csum[b];
            csum[b] = run;
            run += v;
        }
        rowptr[n] = run;
    }
}

__global__ __launch_bounds__(1024) void scanC_kernel(const int* __restrict__ cnt, int n,
                                                     const int* __restrict__ csum,
                                                     int* __restrict__ rowptr,
                                                     int* __restrict__ cursor,
                                                     float* __restrict__ dis)
{
    __shared__ int sdata[1024];
    int t = threadIdx.x;
    int i = blockIdx.x * 1024 + t;
    int v = (i < n) ? cnt[i] : 0;
    sdata[t] = v;
    __syncthreads();
    for (int d = 1; d < 1024; d <<= 1) {
        int x = (t >= d) ? sdata[t - d] : 0;
        __syncthreads();
        sdata[t] += x;
        __syncthreads();
    }
    if (i < n) {
        int excl = csum[blockIdx.x] + sdata[t] - v;
        rowptr[i] = excl;
        cursor[i] = excl;
        dis[i] = rsqrtf((float)(v + 1));   // deg = in-degree + self-loop
    }
}

__global__ void scatter_kernel(const int* __restrict__ src, const int* __restrict__ dst,
                               int E, int* __restrict__ cursor, int* __restrict__ colidx)
{
    int e = blockIdx.x * 256 + threadIdx.x;
    if (e < E) {
        int d = dst[e];
        int pos = atomicAdd(&cursor[d], 1);
        colidx[pos] = src[e];
    }
}

// ---------------- GCN aggregation: one wave per dst node, f16 h, 4x edge unroll
// (r11-proven form: 61.5 us)
__global__ __launch_bounds__(256) void agg_kernel(
    const f16* __restrict__ h, const int* __restrict__ rowptr,
    const int* __restrict__ colidx, const float* __restrict__ dis,
    const float* __restrict__ cb, f16* __restrict__ out, int ldc, int R)
{
    int wid = threadIdx.x >> 6, lane = threadIdx.x & 63;
    int i = blockIdx.x * 4 + wid;
    if (i >= R) return;
    float disi = dis[i];
    f16x4 hv = *(const f16x4*)(h + (long)i * 256 + lane * 4);
    float acc[4];
#pragma unroll
    for (int j = 0; j < 4; ++j) acc[j] = (float)hv[j] * disi;  // self loop
    int e0 = rowptr[i], e1 = rowptr[i + 1];
    int e = e0;
    for (; e + 3 < e1; e += 4) {
        int s0 = colidx[e], s1 = colidx[e + 1], s2 = colidx[e + 2], s3 = colidx[e + 3];
        float w0 = dis[s0], w1 = dis[s1], w2 = dis[s2], w3 = dis[s3];
        f16x4 h0 = *(const f16x4*)(h + (long)s0 * 256 + lane * 4);
        f16x4 h1 = *(const f16x4*)(h + (long)s1 * 256 + lane * 4);
        f16x4 h2 = *(const f16x4*)(h + (long)s2 * 256 + lane * 4);
        f16x4 h3 = *(const f16x4*)(h + (long)s3 * 256 + lane * 4);
#pragma unroll
        for (int j = 0; j < 4; ++j)
            acc[j] += (float)h0[j] * w0 + (float)h1[j] * w1
                    + (float)h2[j] * w2 + (float)h3[j] * w3;
    }
    for (; e < e1; ++e) {
        int s = colidx[e];
        float w = dis[s];
        f16x4 hs = *(const f16x4*)(h + (long)s * 256 + lane * 4);
#pragma unroll
        for (int j = 0; j < 4; ++j) acc[j] += (float)hs[j] * w;
    }
    f16x4 o;
#pragma unroll
    for (int j = 0; j < 4; ++j) {
        float v = acc[j] * disi + cb[lane * 4 + j];
        if (v < 0.f) v = 0.f;
        o[j] = (f16)v;
    }
    *(f16x4*)(out + (long)i * ldc + lane * 4) = o;
}

// ---------------- M = V^T Z via MFMA, two-stage, no atomics
#define VTZ_BLOCKS 192
__global__ __launch_bounds__(256) void vtz_mfma(const f16* __restrict__ t, int ld, int R,
                                                float* __restrict__ Mpart)
{
    __shared__ f16 Vt[112 * 72];
    __shared__ f16 Zt[112 * 72];
    const int tid  = threadIdx.x;
    const int wid  = tid >> 6;
    const int lane = tid & 63;
    const int m    = lane & 15;
    const int quad = lane >> 4;

    for (int idx = tid; idx < 12 * 64; idx += 256) {
        int c = 100 + (idx >> 6), r = idx & 63;
        Vt[c * 72 + r] = (f16)0.f;
        Zt[c * 72 + r] = (f16)0.f;
    }

    f32x4 acc[2][7];
#pragma unroll
    for (int rt = 0; rt < 2; ++rt)
#pragma unroll
        for (int ct = 0; ct < 7; ++ct)
            acc[rt][ct] = f32x4{0.f, 0.f, 0.f, 0.f};

    for (long base = (long)blockIdx.x * 64; base < R; base += (long)gridDim.x * 64) {
        __syncthreads();
        for (int idx = tid; idx < 50 * 64; idx += 256) {
            int r = idx / 50, c2 = (idx - r * 50) * 2;
            f16x2 v2 = f16x2{(f16)0.f, (f16)0.f};
            f16x2 z2 = f16x2{(f16)0.f, (f16)0.f};
            if (base + r < R) {
                v2 = *(const f16x2*)(t + (base + r) * ld + 100 + c2);
                z2 = *(const f16x2*)(t + (base + r) * ld + 200 + c2);
            }
            Vt[c2 * 72 + r] = v2[0]; Vt[(c2 + 1) * 72 + r] = v2[1];
            Zt[c2 * 72 + r] = z2[0]; Zt[(c2 + 1) * 72 + r] = z2[1];
        }
        __syncthreads();
#pragma unroll
        for (int ks = 0; ks < 2; ++ks) {
            int k0 = ks * 32 + quad * 8;
            f16x8 b[7];
#pragma unroll
            for (int ct = 0; ct < 7; ++ct)
                b[ct] = *(const f16x8*)&Zt[(ct * 16 + m) * 72 + k0];
#pragma unroll
            for (int rt = 0; rt < 2; ++rt) {
                int tr = wid + rt * 4;
                if (tr >= 7) continue;
                f16x8 a = *(const f16x8*)&Vt[(tr * 16 + m) * 72 + k0];
#pragma unroll
                for (int ct = 0; ct < 7; ++ct)
                    acc[rt][ct] = __builtin_amdgcn_mfma_f32_16x16x32_f16(a, b[ct], acc[rt][ct], 0, 0, 0);
            }
        }
    }

    float* out = Mpart + (long)blockIdx.x * 10000;
#pragma unroll
    for (int rt = 0; rt < 2; ++rt) {
        int tr = wid + rt * 4;
        if (tr >= 7) continue;
#pragma unroll
        for (int ct = 0; ct < 7; ++ct) {
            int b = ct * 16 + m;
            if (b >= 100) continue;
#pragma unroll
            for (int r = 0; r < 4; ++r) {
                int a = tr * 16 + quad * 4 + r;
                if (a < 100) out[a * 100 + b] = acc[rt][ct][r];
            }
        }
    }
}

// reduce Mpart; compute 1/nf scale inline from csbuf; emit MT = (M*scale)^T as f16.
__global__ __launch_bounds__(256) void vtz_reduce2(const float* __restrict__ Mpart,
                                                   f16* __restrict__ MT,
                                                   const float* __restrict__ cs, int R)
{
    __shared__ float s2[256];
    int t = threadIdx.x;
    float v = (t < 100) ? cs[t] * cs[100 + t] : 0.f;
    s2[t] = v;
    __syncthreads();
    for (int d = 128; d > 0; d >>= 1) {
        if (t < d) s2[t] += s2[t + d];
        __syncthreads();
    }
    float scale = 1.0f / (s2[0] / (float)R + 1e-6f);

    int idx = blockIdx.x * 256 + t;
    if (idx >= 10000) return;
    float s = 0.f;
    for (int b = 0; b < VTZ_BLOCKS; ++b) s += Mpart[(long)b * 10000 + idx];
    s *= scale;
    int a = idx / 100, c = idx - a * 100;     // M[a][c]
    MT[c * 128 + a] = (f16)s;                 // MT[n*128+k] = M[k][n] * scale
}

// ---------------- merged BN finalize + fold
__global__ __launch_bounds__(256) void bn_fold2(
    f16* __restrict__ bigBT,
    const float* __restrict__ cwf, const float* __restrict__ awf,
    const float* __restrict__ bnsum, const float* __restrict__ g,
    const float* __restrict__ bt, int R,
    const float* __restrict__ ab0, float* __restrict__ biascat)
{
    __shared__ float a_s[256], b_s[256];
    const int t = threadIdx.x;
    {
        float s0 = bnsum[t];
        float s1 = bnsum[256 + t];
        float mean = s0 / (float)R;
        float var  = s1 / (float)R - mean * mean;
        if (var < 0.f) var = 0.f;
        float a = g[t] * rsqrtf(var + 1e-5f);
        a_s[t] = a;
        b_s[t] = bt[t] - mean * a;
    }
    __syncthreads();
    const int bid = blockIdx.x;
    if (bid < 768) {
        long idx = (long)bid * 256 + t;              // idx & 255 == t
        bigBT[idx] = (f16)((float)bigBT[idx] * a_s[t]);
    } else if (bid == 768) {
        float s = 0.f;
        for (int k = 0; k < 256; ++k) s += b_s[k] * cwf[(long)k * 256 + t];
        biascat[t] = s;
    } else {
        int n = (bid - 769) * 256 + t;
        if (n < 400) {
            float s = ab0[n];
            for (int k = 0; k < 256; ++k) s += b_s[k] * awf[(long)k * 400 + n];
            biascat[256 + n] = s;
        }
    }
}

// =====================================================================================
extern "C" void kernel_launch(void* const* d_in, const int* in_sizes, int n_in,
                              void* d_out, int out_size, void* d_ws, size_t ws_size,
                              hipStream_t stream)
{
    (void)n_in; (void)out_size; (void)ws_size;
    const int N = in_sizes[0] / 128;       // 50000
    const int E = in_sizes[1] / 2;         // 800000

    const float* x0 = (const float*)d_in[0];
    const int*  ei   = (const int*)d_in[1];
    const int*  esrc = ei;
    const int*  edst = ei + E;
    const float *cw[3], *cbv[3], *aw[3], *abv[3], *rw[3], *rbv[3];
    for (int l = 0; l < 3; ++l) {
        cw[l]  = (const float*)d_in[2 + 6 * l];
        cbv[l] = (const float*)d_in[3 + 6 * l];
        aw[l]  = (const float*)d_in[4 + 6 * l];
        abv[l] = (const float*)d_in[5 + 6 * l];
        rw[l]  = (const float*)d_in[6 + 6 * l];
        rbv[l] = (const float*)d_in[7 + 6 * l];
    }
    const float* g[2]   = {(const float*)d_in[20], (const float*)d_in[22]};
    const float* btb[2] = {(const float*)d_in[21], (const float*)d_in[23]};

    // ---- workspace carve ----
    char* p = (char*)d_ws;
    auto carve = [&](size_t bytes) -> char* {
        char* r = p; p += (bytes + 255) & ~(size_t)255; return r;
    };
    int*   cnt    = (int*)carve((size_t)N * 4);
    int*   rowptr = (int*)carve((size_t)(N + 1) * 4);
    int*   cursor = (int*)carve((size_t)N * 4);
    int*   colidx = (int*)carve((size_t)E * 4);
    float* dis    = (float*)carve((size_t)N * 4);
    int*   csum   = (int*)carve(256 * 4);
    float* Mpart  = (float*)carve((size_t)VTZ_BLOCKS * 10000 * 4);
    // zero region: csbuf0/1/2, bnsumA/B, MT pad
    float* zr     = (float*)carve(9984 * 4);
    float* csbufL[3] = {zr, zr + 256, zr + 512};
    float* bnsumA = zr + 768;
    float* bnsumB = zr + 1280;
    f16*   MT     = (f16*)(zr + 1792);            // 16384 f16
    float* biascat = (float*)carve(768 * 4);
    f16*   WUT    = (f16*)carve(256 * 128 * 2);   // W_U^T [dou][128]
    f16*   bigBT[3], *rwT2[3];
    int din[3] = {128, 256, 256};
    int dou[3] = {256, 256, 128};
    for (int l = 0; l < 3; ++l) {
        bigBT[l] = (f16*)carve((size_t)768 * din[l] * 2);
        rwT2[l]  = (f16*)carve((size_t)dou[l] * 384 * 2);   // rw rows 100..455 -> [dou][384]
    }
    f16*   xbf  = (f16*)carve((size_t)N * 256 * 2);         // current x; pre-BN y for l>=1
    f16*   hb   = (f16*)carve((size_t)N * 256 * 2);
    f16*   tbuf = (f16*)carve((size_t)N * 320 * 2);         // U|V|Z (ld=320, 640B rows)
    f16*   xcat2 = (f16*)carve(((size_t)N * 384 + 64) * 2); // [T|xloc|pad], ld=384 (768B rows)

    // ---- build prep job list ----
    PrepJobs J{};
    int nj = 0; long blk = 0;
    auto addJob = [&](const float* s, void* d, int K, int nc, int Kd, int ty, long elems) {
        J.src[nj] = s; J.dst[nj] = d; J.K[nj] = K; J.ncols[nj] = nc; J.Kd[nj] = Kd;
        J.type[nj] = ty; J.start[nj] = blk; J.elems[nj] = elems;
        blk += (elems + 255) / 256; ++nj;
    };
    for (int l = 0; l < 3; ++l)   // cw -> bigBT cols [0,256)
        addJob(cw[l], bigBT[l], din[l], 256, din[l], 0, (long)256 * din[l]);
    for (int l = 0; l < 3; ++l)   // aw -> bigBT cols [256,768), 400 real + zero pad
        addJob(aw[l], bigBT[l] + (long)256 * din[l], din[l], 400, din[l], 0, (long)512 * din[l]);
    for (int l = 0; l < 3; ++l)   // rw rows 100..455 -> rwT2 [dou][384] (rows 356..383 zero)
        addJob(rw[l] + (long)100 * dou[l], rwT2[l], 356, dou[l], 384, 0, (long)dou[l] * 384);
    addJob(x0, xbf, 0, 0, 0, 1, (long)N * 128);   // cast
    addJob(nullptr, zr, 0, 0, 0, 2, 9984);        // zero csbufs/bnsums/MT
    addJob(nullptr, cnt, 0, 0, 0, 2, N);          // zero cnt (for hist)
    addJob(abv[0], biascat, 0, 0, 0, 3, 768);     // biascat init (layer 0)
    addJob(nullptr, xcat2, 384, 356, 28, 4, (long)N * 28);  // zero xcat2 junk cols 356..383
    J.njobs = nj;

    prep_all<<<(unsigned)blk, 256, 0, stream>>>(J);

    // ---- CSR build ----
    const int nchunks = (N + 1023) / 1024;
    hist_kernel<<<(E + 255) / 256, 256, 0, stream>>>(edst, E, cnt);
    scanA_kernel<<<nchunks, 1024, 0, stream>>>(cnt, N, csum);
    scanB_kernel<<<1, 64, 0, stream>>>(csum, nchunks, N, rowptr);
    scanC_kernel<<<nchunks, 1024, 0, stream>>>(cnt, N, csum, rowptr, cursor, dis);
    scatter_kernel<<<(E + 255) / 256, 256, 0, stream>>>(esrc, edst, E, cursor, colidx);

    int lda = 128;
    const int nrt = (N + 127) / 128;                     // 391 row tiles
    auto grid = [&](int ncb) -> unsigned {
        return (unsigned)(((nrt + 7) / 8) * 8 * ncb);    // padded to XCD groups
    };

    for (int l = 0; l < 3; ++l) {
        float* bnsumX = (l == 0) ? bnsumA : bnsumB;

        // 1) fused: [h | U|V|Z | T] = x @ [cw|aw] (+biascat), colsum fused
        gemm5<<<grid(6), 256, 0, stream>>>(xbf, lda, bigBT[l], din[l],
                                           nullptr, 0, nullptr, 0,
                                           biascat,
                                           nullptr, nullptr, 0, N, 656, 0,
                                           csbufL[l], nullptr,
                                           hb, tbuf, xcat2, 1, nrt, 6);
        // 2) M = V^T Z; reduce computes 1/nf inline -> MT; W_U = Mscaled @ rw1
        vtz_mfma<<<VTZ_BLOCKS, 256, 0, stream>>>(tbuf, 320, N, Mpart);
        vtz_reduce2<<<40, 256, 0, stream>>>(Mpart, MT, csbufL[l], N);
        wu_kernel<<<(dou[l] * 128 + 255) / 256, 256, 0, stream>>>(MT, rw[l], dou[l], WUT);
        // 3) x_local = relu(agg + cb) -> xcat2 cols 100..355
        agg_kernel<<<(N + 3) / 4, 256, 0, stream>>>(hb, rowptr, colidx, dis, cbv[l],
                                                    xcat2 + 100, 384, N);
        // 4) readout: out = U@W_U + [T|xloc]@rw23 (+rb); res never materialized
        if (l < 2) {
            gemm5<<<grid(2), 256, 0, stream>>>(tbuf, 320, WUT, 128,
                                               xcat2, 384, rwT2[l], 384,
                                               rbv[l],
                                               xbf, nullptr, 256, N, 256, 1,
                                               nullptr, bnsumX,
                                               nullptr, nullptr, nullptr, 0, nrt, 2);
            bn_fold2<<<771, 256, 0, stream>>>(bigBT[l + 1], cw[l + 1], aw[l + 1],
                                              bnsumX, g[l], btb[l], N,
                                              abv[l + 1], biascat);
            lda = 256;
        } else {
            gemm5<<<grid(1), 256, 0, stream>>>(tbuf, 320, WUT, 128,
                                               xcat2, 384, rwT2[l], 384,
                                               rbv[l],
                                               nullptr, (float*)d_out, 128, N, 128, 0,
                                               nullptr, nullptr,
                                               nullptr, nullptr, nullptr, 0, nrt, 1);
        }
    }
}